// Round 7
// baseline (150.053 us; speedup 1.0000x reference)
//
#include <hip/hip_runtime.h>

// JointLoss on MI355X. N=8192, D=256. Output: 1 fp32 scalar.
//
// ws layout (bytes):
//   [0,      32768)   pslots[1024][4] float: per-k_rows-block partials (cox,cnt,sim)
//   [32768,  294912)  gsum[2][8192][4] float (per matrix,row,group exp-sums)
//   [294912, +2M)     packed wsi fp8 e4m3 for MX K=128 MFMA:
//                     byte ((ks*4+q)*N + row)*32 + j holds z[row][k],
//                     k = ks*128 + q*32 + j   (ks<2, q<4, j<32)
//   [294912+2M, +4M)  packed omic fp8 (same layout)
//
// R1: same-address atomics serialize -> spread/partial-write instead.
// R5: LDS-BW + exp-VALU bound -> fp8 (half bytes, same MFMA rate).
// R10-R13: symmetric (triangular) k_contrast coverage ABANDONED: 4 variants
//     all 3-4x slow. grid (16,64,2) maps xcd = cb%8 -> R0 shape is L2-local
//     AND balanced; every triangular scheme broke one of the two.
// R14: re-anchored k_contrast = R0 verbatim (~25us). k_rows isolated at
//     45us: VALUBusy 32%, HBM 3.7%, Occ 17.8% -> latency-bound.
// R15: barrier-free direct-global scan, 2 rows/wave, grid 1024 (50% occ).
//     Total 145.8 (best) but serial accounting says k_rows still ~39us:
//     removing barriers + doubling occupancy barely moved it -> the stall
//     is the PER-WAVE critical path (every wave redundantly scans all
//     8192 j = 32 load+exp+compare iterations).
// R16 (this round): split the scan across the block's 4 waves. Each wave
//     scans its QUARTER of j (8 iters) for ALL 8 block rows (rk[8]/ar[8]
//     regs, static unroll); one LDS combine (4x8x2, one barrier); embed/
//     pack phase unchanged (2 rows/wave). Embedding float4 loads hoisted
//     to kernel entry to hide HBM latency under the scan. Per-wave path
//     /4, block L2 read 256->64 KB, occupancy unchanged.

#define NN 8192
#define DD 256

typedef __attribute__((ext_vector_type(4))) float f32x4;
typedef __attribute__((ext_vector_type(4))) int i32x4;
typedef __attribute__((ext_vector_type(8))) int i32x8;

__device__ inline void gl_lds16(const void* g, void* l) {
  // async 16B/lane global->LDS; LDS dst must be wave-uniform base + lane*16
  __builtin_amdgcn_global_load_lds(
      (const __attribute__((address_space(1))) unsigned int*)g,
      (__attribute__((address_space(3))) unsigned int*)l, 16, 0, 0);
}

// ---------------------------------------------------------------------------
// K1 (fused): grid 1024 x 256 thr. Block owns 8 rows.
//  Phase A (split scan): wave wv scans j in [wv*2048, wv*2048+2048) for all
//    8 rows; per-lane float4 reads of L2-resident times/lr, exp inline.
//  Combine: lane-0 partials -> LDS, one barrier, each wave sums 4 partials
//    (fixed order) for its 2 rows.
//  Phase B: norms / cos-sim / Cox li -> pslots; normalize -> fp8 ->
//    rank-permuted MX-packed scatter. Embedding loads issued at entry.
//  First 64 blocks also zero gsum.
// ---------------------------------------------------------------------------
__global__ void __launch_bounds__(256) k_rows(
    const float* __restrict__ lr, const float* __restrict__ times,
    const int* __restrict__ censor,
    const float* __restrict__ wsi, const float* __restrict__ omic,
    unsigned char* __restrict__ pw, unsigned char* __restrict__ po,
    float* __restrict__ pslots, float* __restrict__ gsum) {
  __shared__ int prk[4][8];
  __shared__ float par[4][8];
  __shared__ float red[4][3];
  const int tid = threadIdx.x;
  const int lane = tid & 63;
  const int wv = tid >> 6;
  const int i0 = blockIdx.x * 8;          // block's 8 rows
  const int e0 = i0 + wv * 2;             // wave's 2 embed rows

  if (blockIdx.x < 64) { // zero gsum (65536 floats) across first 64 blocks
    ((f32x4*)gsum)[blockIdx.x * 256 + tid] = (f32x4){0.f, 0.f, 0.f, 0.f};
  }

  // hoist embedding loads: HBM latency hides under the scan
  const float4 w0 = ((const float4*)(wsi + (size_t)e0 * DD))[lane];
  const float4 o0 = ((const float4*)(omic + (size_t)e0 * DD))[lane];
  const float4 w1 = ((const float4*)(wsi + (size_t)(e0 + 1) * DD))[lane];
  const float4 o1 = ((const float4*)(omic + (size_t)(e0 + 1) * DD))[lane];

  float ti[8];
#pragma unroll
  for (int rr = 0; rr < 8; ++rr) ti[rr] = times[i0 + rr];

  // split scan: this wave's quarter of j, all 8 rows
  int rk[8] = {0, 0, 0, 0, 0, 0, 0, 0};
  float ar[8] = {0.f, 0.f, 0.f, 0.f, 0.f, 0.f, 0.f, 0.f};
#pragma unroll
  for (int it = 0; it < 8; ++it) {
    const int p = wv * 512 + it * 64 + lane;  // float4 index
    const float4 t = ((const float4*)times)[p];
    const float4 l = ((const float4*)lr)[p];
    float4 e;
    e.x = __expf(fminf(fmaxf(l.x, -10.f), 10.f));
    e.y = __expf(fminf(fmaxf(l.y, -10.f), 10.f));
    e.z = __expf(fminf(fmaxf(l.z, -10.f), 10.f));
    e.w = __expf(fminf(fmaxf(l.w, -10.f), 10.f));
    const int jb = p * 4;
#define UPD(TV, EV, JJ)                                                  \
  {                                                                      \
    _Pragma("unroll") for (int rr = 0; rr < 8; ++rr) {                   \
      const bool c1 = ((TV) < ti[rr]) ||                                 \
                      (((TV) == ti[rr]) && ((JJ) < i0 + rr));            \
      rk[rr] += c1 ? 1 : 0;                                              \
      ar[rr] += c1 ? 0.f : (EV);                                         \
    }                                                                    \
  }
    UPD(t.x, e.x, jb + 0)
    UPD(t.y, e.y, jb + 1)
    UPD(t.z, e.z, jb + 2)
    UPD(t.w, e.w, jb + 3)
#undef UPD
  }
#pragma unroll
  for (int m = 1; m < 64; m <<= 1) {
#pragma unroll
    for (int rr = 0; rr < 8; ++rr) {
      rk[rr] += __shfl_xor(rk[rr], m);
      ar[rr] += __shfl_xor(ar[rr], m);
    }
  }
  if (lane < 8) {
    // lane rr stores row rr's partial (values are lane-uniform post-reduce)
#pragma unroll
    for (int rr = 0; rr < 8; ++rr) {
      if (lane == rr) { prk[wv][rr] = rk[rr]; par[wv][rr] = ar[rr]; }
    }
  }
  __syncthreads();

  // per-row phase: wave handles rows e0, e0+1 (local idx wv*2, wv*2+1)
  float scox = 0.f, scnt = 0.f, ssim = 0.f;
#pragma unroll
  for (int rr = 0; rr < 2; ++rr) {
    const int li = wv * 2 + rr;
    const int i = i0 + li;
    const int rkf = prk[0][li] + prk[1][li] + prk[2][li] + prk[3][li];
    const float arf = par[0][li] + par[1][li] + par[2][li] + par[3][li];
    const float4 w = rr ? w1 : w0;
    const float4 o = rr ? o1 : o0;
    float nw = w.x * w.x + w.y * w.y + w.z * w.z + w.w * w.w;
    float no = o.x * o.x + o.y * o.y + o.z * o.z + o.w * o.w;
    float dd = w.x * o.x + w.y * o.y + w.z * o.z + w.w * o.w;
#pragma unroll
    for (int m = 1; m < 64; m <<= 1) {
      nw += __shfl_xor(nw, m);
      no += __shfl_xor(no, m);
      dd += __shfl_xor(dd, m);
    }
    const float nws = sqrtf(nw), nos = sqrtf(no);
    if (lane == 0) {
      float cc = dd / (fmaxf(nws, 1e-8f) * fmaxf(nos, 1e-8f));
      cc = fminf(fmaxf(cc, -1.f), 1.f);
      const float l = fminf(fmaxf(lr[i], -10.f), 10.f);
      const float li2 = l - logf(arf + 1e-15f);
      if (censor[i] == 1) { scox += li2; scnt += 1.f; }
      ssim += 1.f - cc;
    }
    // normalize -> fp8 -> rank-permuted MX-packed scatter
    // lane covers k = lane*4..+3: ks=lane>>5, q=(lane>>3)&3, j=(lane&7)*4
    const float iw = 1.f / fmaxf(nws, 1e-12f);
    const float io = 1.f / fmaxf(nos, 1e-12f);
    int zw = __builtin_amdgcn_cvt_pk_fp8_f32(w.x * iw, w.y * iw, 0, false);
    zw = __builtin_amdgcn_cvt_pk_fp8_f32(w.z * iw, w.w * iw, zw, true);
    int zo = __builtin_amdgcn_cvt_pk_fp8_f32(o.x * io, o.y * io, 0, false);
    zo = __builtin_amdgcn_cvt_pk_fp8_f32(o.z * io, o.w * io, zo, true);
    const size_t off =
        ((size_t)((lane >> 5) * 4 + ((lane >> 3) & 3)) * NN + rkf) * 32 +
        (lane & 7) * 4;
    *(unsigned int*)(pw + off) = (unsigned int)zw;
    *(unsigned int*)(po + off) = (unsigned int)zo;
  }
  if (lane == 0) {
    red[wv][0] = scox; red[wv][1] = scnt; red[wv][2] = ssim;
  }
  __syncthreads();
  if (tid < 3) { // non-atomic per-block partial (every slot written -> no init)
    pslots[blockIdx.x * 4 + tid] =
        red[0][tid] + red[1][tid] + red[2][tid] + red[3][tid];
  }
}

// ---------------------------------------------------------------------------
// K2: contrastive exp-sums, MX fp8 K=128. grid (16 cb, 64 rb, 2 mz) x 256
// thr, launch_bounds(256,4) -> 128-reg budget, 4 blocks/CU.
// Block = 128 rows x 512 cols (8 stages x 64 cols). Wave owns 32 rows:
// afrag[2 rt][2 ks] i32x8 = 32 regs resident. B double-buffered LDS
// 2 x 16 KB via global_load_lds (4 chunks/wave/stage).
// NOTE: xcd = bid%8 = cb%8 -> all 64 rb-blocks of a cb land on ONE XCD:
// B-panel (128 KB) is L2-local and the grid is perfectly XCD-balanced.
// (R10-R13 broke one or both; do not change this grid shape.)
//
// MX operand layout: lane(q,lo) holds 32 B = X[lo][k = ks*128 + q*32..+31];
// unit scale 0x7F. LDS: region(ct,ks,h) = ((ct*2+ks)*2+h)*1024; lane l
// holds 16 B (k half h) at region + l*16 -> two lane-linear ds_read_b128
// per frag, conflict-free. DMA chunk u=(wv*4+p)*64+lane writes byte u*16;
// decode ct=u>>8, ks=(u>>7)&1, h=(u>>6)&1, l=u&63 -> src
// pk + ((ks*4+(l>>4))*NN + col)*32 + h*16, col = colstart+ct*16+(l&15).
// Group constant per block: g = cb>>2. Diagonal: wave rows are the
// (wv&1)-half of a 64-col window -> excl when ct==(wv&1)*2+rt && lo==q*4+r.
// ---------------------------------------------------------------------------
__global__ void __launch_bounds__(256, 4) k_contrast(
    const unsigned char* __restrict__ pw, const unsigned char* __restrict__ po,
    float* __restrict__ gsum) {
  __shared__ __align__(16) unsigned char sbuf[2][16384]; // 2 x 16 KB
  const int tid = threadIdx.x;
  const int lane = tid & 63;
  const int wv = tid >> 6;                 // 0..3
  const int lo = lane & 15, q = lane >> 4; // MFMA frag coords
  const int cb = blockIdx.x, rb = blockIdx.y, mz = blockIdx.z;
  const unsigned char* __restrict__ pk = (mz == 0) ? pw : po;
  const int rowbase = rb * 128 + wv * 32;
  const int colstart = cb * 512;
  const int g = cb >> 2;

  // A fragments: 2 row-tiles x 2 K-segments x 32 B = 32 regs, resident
  i32x8 afrag[2][2];
#pragma unroll
  for (int rt = 0; rt < 2; ++rt) {
    const size_t row = rowbase + rt * 16 + lo;
#pragma unroll
    for (int ks = 0; ks < 2; ++ks)
      afrag[rt][ks] = *(const i32x8*)(pk + ((size_t)(ks * 4 + q) * NN + row) * 32);
  }

  // per-lane DMA sources, 4 chunks/wave (advance +2048 B per stage = +64 cols)
  const unsigned char* gsrc[4];
#pragma unroll
  for (int p = 0; p < 4; ++p) {
    const int u = (wv * 4 + p) * 64 + lane;
    const int uct = u >> 8, uks = (u >> 7) & 1, uh = (u >> 6) & 1;
    const int ul = u & 63;
    gsrc[p] = pk + ((size_t)(uks * 4 + (ul >> 4)) * NN
                    + colstart + uct * 16 + (ul & 15)) * 32 + uh * 16;
  }
  unsigned char* const ldb = &sbuf[0][(size_t)wv * 4096];

#pragma unroll
  for (int p = 0; p < 4; ++p) gl_lds16(gsrc[p], ldb + p * 1024);
  __syncthreads();

  float s[2][4] = {{0.f}};
  const int dctbase = (wv & 1) * 2; // wave's 32 rows within the 64-col window

#pragma unroll 1
  for (int st = 0; st < 8; ++st) {
    if (st < 7) { // async-prefetch next stage into other buffer
      const size_t adv = (size_t)(st + 1) * 2048;
      const size_t bofs = ((st + 1) & 1) ? 16384 : 0;
#pragma unroll
      for (int p = 0; p < 4; ++p) gl_lds16(gsrc[p] + adv, ldb + bofs + p * 1024);
    }
    const unsigned char* buf = &sbuf[st & 1][0];
    const bool diagw = ((rowbase >> 6) == ((colstart + st * 64) >> 6));
#pragma unroll
    for (int ct = 0; ct < 4; ++ct) {
      f32x4 a0 = {0.f, 0.f, 0.f, 0.f}, a1 = {0.f, 0.f, 0.f, 0.f};
#pragma unroll
      for (int ks = 0; ks < 2; ++ks) {
        const int rbase = ((ct * 2 + ks) * 2) * 1024 + lane * 16;
        i32x4 blo = *(const i32x4*)&buf[rbase];
        i32x4 bhi = *(const i32x4*)&buf[rbase + 1024];
        i32x8 b = __builtin_shufflevector(blo, bhi, 0, 1, 2, 3, 4, 5, 6, 7);
        // unit scales (E8M0 0x7F = 2^0); fmt 0 = fp8 e4m3 for A and B
        a0 = __builtin_amdgcn_mfma_scale_f32_16x16x128_f8f6f4(
            afrag[0][ks], b, a0, 0, 0, 0, 0x7F, 0, 0x7F);
        a1 = __builtin_amdgcn_mfma_scale_f32_16x16x128_f8f6f4(
            afrag[1][ks], b, a1, 0, 0, 0, 0x7F, 0, 0x7F);
      }
      // epilogue: exp(sim-10) = 2^(14.427*dot - 14.427), sim = dot/0.1 <= 10
      if (diagw) {
#pragma unroll
        for (int r = 0; r < 4; ++r) {
          float e0 = __builtin_amdgcn_exp2f(fmaf(a0[r], 14.4269504f, -14.4269504f));
          float e1 = __builtin_amdgcn_exp2f(fmaf(a1[r], 14.4269504f, -14.4269504f));
          if (ct == dctbase + 0 && lo == q * 4 + r) e0 = 0.f; // exact diagonal
          if (ct == dctbase + 1 && lo == q * 4 + r) e1 = 0.f;
          s[0][r] += e0;
          s[1][r] += e1;
        }
      } else {
#pragma unroll
        for (int r = 0; r < 4; ++r) {
          s[0][r] += __builtin_amdgcn_exp2f(fmaf(a0[r], 14.4269504f, -14.4269504f));
          s[1][r] += __builtin_amdgcn_exp2f(fmaf(a1[r], 14.4269504f, -14.4269504f));
        }
      }
    }
    __syncthreads();
  }

  // flush: reduce over 16 col-lanes, one atomic per (row, group)
#pragma unroll
  for (int rt = 0; rt < 2; ++rt)
#pragma unroll
    for (int r = 0; r < 4; ++r) {
      float v = s[rt][r];
      v += __shfl_xor(v, 1); v += __shfl_xor(v, 2);
      v += __shfl_xor(v, 4); v += __shfl_xor(v, 8);
      if (lo == 0) {
        const int row = rowbase + rt * 16 + q * 4 + r; // C/D: row=(lane>>4)*4+reg
        atomicAdd(&gsum[((size_t)mz * NN + row) * 4 + g], v);
      }
    }
}

// ---------------------------------------------------------------------------
// K3: finale. One block, 1024 thr. Reduces pslots (cox,cnt,sim), computes
// per-row LSE differences from gsum, combines the scalar.
// ---------------------------------------------------------------------------
__global__ void __launch_bounds__(1024) k_finale(
    const float* __restrict__ pslots, const float* __restrict__ gsum,
    float* __restrict__ out) {
  __shared__ float rsum[16][4];
  const int tid = threadIdx.x;
  const int lane = tid & 63, wv = tid >> 6;
  float cox = 0.f, cnt = 0.f, sim = 0.f, con = 0.f;
  for (int b = tid; b < 1024; b += 1024) {
    const float4 v = ((const float4*)pslots)[b];
    cox += v.x; cnt += v.y; sim += v.z;
  }
  for (int idx = tid; idx < 2 * NN; idx += 1024) {
    const float4 v = ((const float4*)gsum)[idx];
    const int row = idx & (NN - 1);
    const int gg = row >> 11; // group of permuted row
    const float sg = (gg == 0) ? v.x : (gg == 1) ? v.y : (gg == 2) ? v.z : v.w;
    con += logf(v.x + v.y + v.z + v.w) - logf(sg); // fixed shifts cancel
  }
  for (int m = 1; m < 64; m <<= 1) {
    cox += __shfl_xor(cox, m);
    cnt += __shfl_xor(cnt, m);
    sim += __shfl_xor(sim, m);
    con += __shfl_xor(con, m);
  }
  if (lane == 0) {
    rsum[wv][0] = cox; rsum[wv][1] = cnt; rsum[wv][2] = sim; rsum[wv][3] = con;
  }
  __syncthreads();
  if (tid == 0) {
    float c0 = 0.f, c1 = 0.f, c2 = 0.f, c3 = 0.f;
    for (int k = 0; k < 16; ++k) {
      c0 += rsum[k][0]; c1 += rsum[k][1]; c2 += rsum[k][2]; c3 += rsum[k][3];
    }
    out[0] = -c0 / fmaxf(c1, 1.f) + c2 / (float)NN
             + 0.1f * 0.5f * c3 / (float)NN;
  }
}

extern "C" void kernel_launch(void* const* d_in, const int* in_sizes, int n_in,
                              void* d_out, int out_size, void* d_ws, size_t ws_size,
                              hipStream_t stream) {
  const float* lr = (const float*)d_in[0];
  const float* times = (const float*)d_in[1];
  const int* censor = (const int*)d_in[2];
  const float* wsi = (const float*)d_in[3];
  const float* omic = (const float*)d_in[4];
  float* out = (float*)d_out;

  char* ws = (char*)d_ws;
  float* pslots = (float*)ws;
  float* gsum = (float*)(ws + 32768);
  unsigned char* pw = (unsigned char*)(ws + 294912);
  unsigned char* po = (unsigned char*)(ws + 294912 + 2097152);

  k_rows<<<1024, 256, 0, stream>>>(lr, times, censor, wsi, omic, pw, po, pslots, gsum);
  k_contrast<<<dim3(16, 64, 2), 256, 0, stream>>>(pw, po, gsum);
  k_finale<<<1, 1024, 0, stream>>>(pslots, gsum, out);
}

// Round 8
// 145.205 us; speedup vs baseline: 1.0334x; 1.0334x over previous
//
#include <hip/hip_runtime.h>

// JointLoss on MI355X. N=8192, D=256. Output: 1 fp32 scalar.
//
// ws layout (bytes):
//   [0,      32768)   pslots[1024][4] float: per-k_rows-block partials (cox,cnt,sim)
//   [32768,  294912)  gsum[2][8192][4] float (per matrix,row,group exp-sums)
//   [294912, +2M)     packed wsi fp8 e4m3 for MX K=128 MFMA:
//                     byte ((ks*4+q)*N + row)*32 + j holds SCL*z[row][k],
//                     k = ks*128 + q*32 + j   (ks<2, q<4, j<32)
//   [294912+2M, +4M)  packed omic fp8 (same layout)
//
// R1: same-address atomics serialize -> spread/partial-write instead.
// R5: LDS-BW + exp-VALU bound -> fp8 (half bytes, same MFMA rate).
// R10-R13: symmetric (triangular) k_contrast coverage ABANDONED: 4 variants
//     all 3-4x slow. grid (16,64,2) maps xcd = cb%8 -> R0 shape is L2-local
//     AND balanced; every triangular scheme broke one of the two.
// R14: re-anchor. k_rows isolated at 45us (latency-bound chunk loop).
// R15: barrier-free direct-global scan, 2 rows/wave, grid 1024. 145.8 best.
// R16: split-scan across waves (4x fewer loads/wave) -> +4.3us REGRESSION.
//     With R15 (barriers+occupancy) this kills the "k_rows still 39us"
//     estimate: k_rows is ~12-15us; serial accounting was confounded by
//     +-5us run-to-run noise in the ~103us harness fill/overhead floor
//     (R0 same kernel measured 146.0 and 149.1). Revert to R15 k_rows.
// R17 (this round): consolidation. R15 k_rows verbatim + k_contrast with
//     SCL = sqrt(log2(e)/T) baked into the fp8 pack -> epilogue is bare
//     exp2(a[r]) (deletes 8 fma per (st,ct) per thread, ~25% of epilogue
//     VALU). Numerics validated in R10-R13 (all passed, absmax 0.0):
//     fp8 relative grid is scale-invariant, |z*SCL| <= 3.8 << 448, row
//     sums <= 1.8e8 (fp32-safe), constant factor cancels in finale's
//     log(sum)-log(sg). Predicted k_contrast 25 -> ~22us, total ~142-144.
//     If >=145: controllable kernels are inside harness-floor noise ->
//     declare roofline.

#define NN 8192
#define DD 256
#define SCL 3.7982826f  // sqrt(14.4269504) ; dot' = 14.4269504 * cos

typedef __attribute__((ext_vector_type(4))) float f32x4;
typedef __attribute__((ext_vector_type(4))) int i32x4;
typedef __attribute__((ext_vector_type(8))) int i32x8;

__device__ inline void gl_lds16(const void* g, void* l) {
  // async 16B/lane global->LDS; LDS dst must be wave-uniform base + lane*16
  __builtin_amdgcn_global_load_lds(
      (const __attribute__((address_space(1))) unsigned int*)g,
      (__attribute__((address_space(3))) unsigned int*)l, 16, 0, 0);
}

// ---------------------------------------------------------------------------
// K1 (fused): grid 1024 x 256 thr (4 waves, 2 rows each).  [R15 verbatim
// except SCL in the pack scale]
//  - rank_i / at_risk_i: barrier-free direct-global scan. Lane reads its
//    float4 j-slice of times/lr (L2-resident, 64KB), computes exp inline,
//    compares vs 2 resident rows; wave shuffle-reduce at the end.
//  - norms / cos-sim / Cox li -> non-atomic per-block partial in pslots[blk].
//  - normalize * SCL -> fp8 -> scatter into rank-permuted MX-packed layout.
//  - first 64 blocks also zero gsum.
// ---------------------------------------------------------------------------
__global__ void __launch_bounds__(256) k_rows(
    const float* __restrict__ lr, const float* __restrict__ times,
    const int* __restrict__ censor,
    const float* __restrict__ wsi, const float* __restrict__ omic,
    unsigned char* __restrict__ pw, unsigned char* __restrict__ po,
    float* __restrict__ pslots, float* __restrict__ gsum) {
  __shared__ float red[4][3];
  const int tid = threadIdx.x;
  const int lane = tid & 63;
  const int wv = tid >> 6;
  const int i0 = blockIdx.x * 8 + wv * 2;  // wave's 2 rows: i0, i0+1

  if (blockIdx.x < 64) { // zero gsum (65536 floats) across first 64 blocks
    ((f32x4*)gsum)[blockIdx.x * 256 + tid] = (f32x4){0.f, 0.f, 0.f, 0.f};
  }

  float ti[2];
#pragma unroll
  for (int rr = 0; rr < 2; ++rr) ti[rr] = times[i0 + rr];

  // rank + at_risk: barrier-free scan of all 8192 j, float4 per lane-iter
  int rk[2] = {0, 0};
  float ar[2] = {0.f, 0.f};
#pragma unroll 4
  for (int it = 0; it < 32; ++it) {
    const int p = it * 64 + lane;  // float4 index
    const float4 t = ((const float4*)times)[p];
    const float4 l = ((const float4*)lr)[p];
    float4 e;
    e.x = __expf(fminf(fmaxf(l.x, -10.f), 10.f));
    e.y = __expf(fminf(fmaxf(l.y, -10.f), 10.f));
    e.z = __expf(fminf(fmaxf(l.z, -10.f), 10.f));
    e.w = __expf(fminf(fmaxf(l.w, -10.f), 10.f));
    const int jb = p * 4;
#define UPD(TV, EV, JJ)                                                  \
  {                                                                      \
    _Pragma("unroll") for (int rr = 0; rr < 2; ++rr) {                   \
      const bool c1 = ((TV) < ti[rr]) ||                                 \
                      (((TV) == ti[rr]) && ((JJ) < i0 + rr));            \
      rk[rr] += c1 ? 1 : 0;                                              \
      ar[rr] += c1 ? 0.f : (EV);                                         \
    }                                                                    \
  }
    UPD(t.x, e.x, jb + 0)
    UPD(t.y, e.y, jb + 1)
    UPD(t.z, e.z, jb + 2)
    UPD(t.w, e.w, jb + 3)
#undef UPD
  }
#pragma unroll
  for (int m = 1; m < 64; m <<= 1) {
#pragma unroll
    for (int rr = 0; rr < 2; ++rr) {
      rk[rr] += __shfl_xor(rk[rr], m);
      ar[rr] += __shfl_xor(ar[rr], m);
    }
  }

  // per-row: embeddings (loaded once, post-scan), norms, pack + scatter
  float scox = 0.f, scnt = 0.f, ssim = 0.f;
#pragma unroll
  for (int rr = 0; rr < 2; ++rr) {
    const int i = i0 + rr;
    const float4 w = ((const float4*)(wsi + (size_t)i * DD))[lane];
    const float4 o = ((const float4*)(omic + (size_t)i * DD))[lane];
    float nw = w.x * w.x + w.y * w.y + w.z * w.z + w.w * w.w;
    float no = o.x * o.x + o.y * o.y + o.z * o.z + o.w * o.w;
    float dd = w.x * o.x + w.y * o.y + w.z * o.z + w.w * o.w;
#pragma unroll
    for (int m = 1; m < 64; m <<= 1) {
      nw += __shfl_xor(nw, m);
      no += __shfl_xor(no, m);
      dd += __shfl_xor(dd, m);
    }
    const float nws = sqrtf(nw), nos = sqrtf(no);
    if (lane == 0) {
      float cc = dd / (fmaxf(nws, 1e-8f) * fmaxf(nos, 1e-8f));
      cc = fminf(fmaxf(cc, -1.f), 1.f);
      const float l = fminf(fmaxf(lr[i], -10.f), 10.f);
      const float li = l - logf(ar[rr] + 1e-15f);
      if (censor[i] == 1) { scox += li; scnt += 1.f; }
      ssim += 1.f - cc;
    }
    // normalize * SCL -> fp8 -> rank-permuted MX-packed scatter
    // lane covers k = lane*4..+3: ks=lane>>5, q=(lane>>3)&3, j=(lane&7)*4
    const float iw = SCL / fmaxf(nws, 1e-12f);
    const float io = SCL / fmaxf(nos, 1e-12f);
    int zw = __builtin_amdgcn_cvt_pk_fp8_f32(w.x * iw, w.y * iw, 0, false);
    zw = __builtin_amdgcn_cvt_pk_fp8_f32(w.z * iw, w.w * iw, zw, true);
    int zo = __builtin_amdgcn_cvt_pk_fp8_f32(o.x * io, o.y * io, 0, false);
    zo = __builtin_amdgcn_cvt_pk_fp8_f32(o.z * io, o.w * io, zo, true);
    const size_t off =
        ((size_t)((lane >> 5) * 4 + ((lane >> 3) & 3)) * NN + rk[rr]) * 32 +
        (lane & 7) * 4;
    *(unsigned int*)(pw + off) = (unsigned int)zw;
    *(unsigned int*)(po + off) = (unsigned int)zo;
  }
  if (lane == 0) {
    red[wv][0] = scox; red[wv][1] = scnt; red[wv][2] = ssim;
  }
  __syncthreads();
  if (tid < 3) { // non-atomic per-block partial (every slot written -> no init)
    pslots[blockIdx.x * 4 + tid] =
        red[0][tid] + red[1][tid] + red[2][tid] + red[3][tid];
  }
}

// ---------------------------------------------------------------------------
// K2: contrastive exp-sums, MX fp8 K=128. grid (16 cb, 64 rb, 2 mz) x 256
// thr, launch_bounds(256,4) -> 128-reg budget, 4 blocks/CU.
// Block = 128 rows x 512 cols (8 stages x 64 cols). Wave owns 32 rows:
// afrag[2 rt][2 ks] i32x8 = 32 regs resident. B double-buffered LDS
// 2 x 16 KB via global_load_lds (4 chunks/wave/stage).
// NOTE: xcd = bid%8 = cb%8 -> all 64 rb-blocks of a cb land on ONE XCD:
// B-panel (128 KB) is L2-local and the grid is perfectly XCD-balanced.
// (R10-R13 broke one or both; do not change this grid shape.)
//
// MX operand layout: lane(q,lo) holds 32 B = X[lo][k = ks*128 + q*32..+31];
// unit scale 0x7F. LDS: region(ct,ks,h) = ((ct*2+ks)*2+h)*1024; lane l
// holds 16 B (k half h) at region + l*16 -> two lane-linear ds_read_b128
// per frag, conflict-free. DMA chunk u=(wv*4+p)*64+lane writes byte u*16;
// decode ct=u>>8, ks=(u>>7)&1, h=(u>>6)&1, l=u&63 -> src
// pk + ((ks*4+(l>>4))*NN + col)*32 + h*16, col = colstart+ct*16+(l&15).
// Group constant per block: g = cb>>2. Diagonal: wave rows are the
// (wv&1)-half of a 64-col window -> excl when ct==(wv&1)*2+rt && lo==q*4+r.
// R17: SCL baked into pack -> epilogue is bare exp2(a[r]) (no fma, no
// bias; constant factor cancels in finale's log difference).
// ---------------------------------------------------------------------------
__global__ void __launch_bounds__(256, 4) k_contrast(
    const unsigned char* __restrict__ pw, const unsigned char* __restrict__ po,
    float* __restrict__ gsum) {
  __shared__ __align__(16) unsigned char sbuf[2][16384]; // 2 x 16 KB
  const int tid = threadIdx.x;
  const int lane = tid & 63;
  const int wv = tid >> 6;                 // 0..3
  const int lo = lane & 15, q = lane >> 4; // MFMA frag coords
  const int cb = blockIdx.x, rb = blockIdx.y, mz = blockIdx.z;
  const unsigned char* __restrict__ pk = (mz == 0) ? pw : po;
  const int rowbase = rb * 128 + wv * 32;
  const int colstart = cb * 512;
  const int g = cb >> 2;

  // A fragments: 2 row-tiles x 2 K-segments x 32 B = 32 regs, resident
  i32x8 afrag[2][2];
#pragma unroll
  for (int rt = 0; rt < 2; ++rt) {
    const size_t row = rowbase + rt * 16 + lo;
#pragma unroll
    for (int ks = 0; ks < 2; ++ks)
      afrag[rt][ks] = *(const i32x8*)(pk + ((size_t)(ks * 4 + q) * NN + row) * 32);
  }

  // per-lane DMA sources, 4 chunks/wave (advance +2048 B per stage = +64 cols)
  const unsigned char* gsrc[4];
#pragma unroll
  for (int p = 0; p < 4; ++p) {
    const int u = (wv * 4 + p) * 64 + lane;
    const int uct = u >> 8, uks = (u >> 7) & 1, uh = (u >> 6) & 1;
    const int ul = u & 63;
    gsrc[p] = pk + ((size_t)(uks * 4 + (ul >> 4)) * NN
                    + colstart + uct * 16 + (ul & 15)) * 32 + uh * 16;
  }
  unsigned char* const ldb = &sbuf[0][(size_t)wv * 4096];

#pragma unroll
  for (int p = 0; p < 4; ++p) gl_lds16(gsrc[p], ldb + p * 1024);
  __syncthreads();

  float s[2][4] = {{0.f}};
  const int dctbase = (wv & 1) * 2; // wave's 32 rows within the 64-col window

#pragma unroll 1
  for (int st = 0; st < 8; ++st) {
    if (st < 7) { // async-prefetch next stage into other buffer
      const size_t adv = (size_t)(st + 1) * 2048;
      const size_t bofs = ((st + 1) & 1) ? 16384 : 0;
#pragma unroll
      for (int p = 0; p < 4; ++p) gl_lds16(gsrc[p] + adv, ldb + bofs + p * 1024);
    }
    const unsigned char* buf = &sbuf[st & 1][0];
    const bool diagw = ((rowbase >> 6) == ((colstart + st * 64) >> 6));
#pragma unroll
    for (int ct = 0; ct < 4; ++ct) {
      f32x4 a0 = {0.f, 0.f, 0.f, 0.f}, a1 = {0.f, 0.f, 0.f, 0.f};
#pragma unroll
      for (int ks = 0; ks < 2; ++ks) {
        const int rbase = ((ct * 2 + ks) * 2) * 1024 + lane * 16;
        i32x4 blo = *(const i32x4*)&buf[rbase];
        i32x4 bhi = *(const i32x4*)&buf[rbase + 1024];
        i32x8 b = __builtin_shufflevector(blo, bhi, 0, 1, 2, 3, 4, 5, 6, 7);
        // unit scales (E8M0 0x7F = 2^0); fmt 0 = fp8 e4m3 for A and B
        a0 = __builtin_amdgcn_mfma_scale_f32_16x16x128_f8f6f4(
            afrag[0][ks], b, a0, 0, 0, 0, 0x7F, 0, 0x7F);
        a1 = __builtin_amdgcn_mfma_scale_f32_16x16x128_f8f6f4(
            afrag[1][ks], b, a1, 0, 0, 0, 0x7F, 0, 0x7F);
      }
      // epilogue: e = exp2(dot') with dot' = 14.4269504*cos (SCL baked)
      if (diagw) {
#pragma unroll
        for (int r = 0; r < 4; ++r) {
          float e0 = __builtin_amdgcn_exp2f(a0[r]);
          float e1 = __builtin_amdgcn_exp2f(a1[r]);
          if (ct == dctbase + 0 && lo == q * 4 + r) e0 = 0.f; // exact diagonal
          if (ct == dctbase + 1 && lo == q * 4 + r) e1 = 0.f;
          s[0][r] += e0;
          s[1][r] += e1;
        }
      } else {
#pragma unroll
        for (int r = 0; r < 4; ++r) {
          s[0][r] += __builtin_amdgcn_exp2f(a0[r]);
          s[1][r] += __builtin_amdgcn_exp2f(a1[r]);
        }
      }
    }
    __syncthreads();
  }

  // flush: reduce over 16 col-lanes, one atomic per (row, group)
#pragma unroll
  for (int rt = 0; rt < 2; ++rt)
#pragma unroll
    for (int r = 0; r < 4; ++r) {
      float v = s[rt][r];
      v += __shfl_xor(v, 1); v += __shfl_xor(v, 2);
      v += __shfl_xor(v, 4); v += __shfl_xor(v, 8);
      if (lo == 0) {
        const int row = rowbase + rt * 16 + q * 4 + r; // C/D: row=(lane>>4)*4+reg
        atomicAdd(&gsum[((size_t)mz * NN + row) * 4 + g], v);
      }
    }
}

// ---------------------------------------------------------------------------
// K3: finale. One block, 1024 thr. Reduces pslots (cox,cnt,sim), computes
// per-row LSE differences from gsum, combines the scalar.
// ---------------------------------------------------------------------------
__global__ void __launch_bounds__(1024) k_finale(
    const float* __restrict__ pslots, const float* __restrict__ gsum,
    float* __restrict__ out) {
  __shared__ float rsum[16][4];
  const int tid = threadIdx.x;
  const int lane = tid & 63, wv = tid >> 6;
  float cox = 0.f, cnt = 0.f, sim = 0.f, con = 0.f;
  for (int b = tid; b < 1024; b += 1024) {
    const float4 v = ((const float4*)pslots)[b];
    cox += v.x; cnt += v.y; sim += v.z;
  }
  for (int idx = tid; idx < 2 * NN; idx += 1024) {
    const float4 v = ((const float4*)gsum)[idx];
    const int row = idx & (NN - 1);
    const int gg = row >> 11; // group of permuted row
    const float sg = (gg == 0) ? v.x : (gg == 1) ? v.y : (gg == 2) ? v.z : v.w;
    con += logf(v.x + v.y + v.z + v.w) - logf(sg); // scale factor cancels
  }
  for (int m = 1; m < 64; m <<= 1) {
    cox += __shfl_xor(cox, m);
    cnt += __shfl_xor(cnt, m);
    sim += __shfl_xor(sim, m);
    con += __shfl_xor(con, m);
  }
  if (lane == 0) {
    rsum[wv][0] = cox; rsum[wv][1] = cnt; rsum[wv][2] = sim; rsum[wv][3] = con;
  }
  __syncthreads();
  if (tid == 0) {
    float c0 = 0.f, c1 = 0.f, c2 = 0.f, c3 = 0.f;
    for (int k = 0; k < 16; ++k) {
      c0 += rsum[k][0]; c1 += rsum[k][1]; c2 += rsum[k][2]; c3 += rsum[k][3];
    }
    out[0] = -c0 / fmaxf(c1, 1.f) + c2 / (float)NN
             + 0.1f * 0.5f * c3 / (float)NN;
  }
}

extern "C" void kernel_launch(void* const* d_in, const int* in_sizes, int n_in,
                              void* d_out, int out_size, void* d_ws, size_t ws_size,
                              hipStream_t stream) {
  const float* lr = (const float*)d_in[0];
  const float* times = (const float*)d_in[1];
  const int* censor = (const int*)d_in[2];
  const float* wsi = (const float*)d_in[3];
  const float* omic = (const float*)d_in[4];
  float* out = (float*)d_out;

  char* ws = (char*)d_ws;
  float* pslots = (float*)ws;
  float* gsum = (float*)(ws + 32768);
  unsigned char* pw = (unsigned char*)(ws + 294912);
  unsigned char* po = (unsigned char*)(ws + 294912 + 2097152);

  k_rows<<<1024, 256, 0, stream>>>(lr, times, censor, wsi, omic, pw, po, pslots, gsum);
  k_contrast<<<dim3(16, 64, 2), 256, 0, stream>>>(pw, po, gsum);
  k_finale<<<1, 1024, 0, stream>>>(pslots, gsum, out);
}